// Round 13
// baseline (686.169 us; speedup 1.0000x reference)
//
#include <hip/hip_runtime.h>
#include <hip/hip_bf16.h>
#include <math.h>

// Problem constants (from reference setup_inputs)
#define BB 32
#define NN 1024
#define DD 64
#define TT 2048
#define CHUNKS (TT / 256)   // 8 column-chunks of 256 (segsum)
#define SEGS 16             // n-segments (decoupled scan)

typedef float f32x4 __attribute__((ext_vector_type(4)));

// alpha in LOG2 units: exp() becomes bare v_exp_f32. Validated R9/R10/R12.
#define NLOG2E_HALF (-0.72134752044448169f)   // -0.5 * log2(e)

__device__ __forceinline__ float exp2_fast(float x) {
    return __builtin_amdgcn_exp2f(x);
}

// DPP move WITHOUT tied-old operand -> fuses into the consumer op.
template<int CTRL>
__device__ __forceinline__ float dpp_mov_f(float v) {
    return __int_as_float(
        __builtin_amdgcn_mov_dpp(__float_as_int(v), CTRL, 0xF, 0xF, true));
}

// All-lanes butterfly reduce over groups of 2^GB lanes.
template<int GB>
__device__ __forceinline__ float groupMax(float v) {
    v = fmaxf(v, dpp_mov_f<0x0B1>(v));  // xor1
    v = fmaxf(v, dpp_mov_f<0x04E>(v));  // xor2
    v = fmaxf(v, dpp_mov_f<0x141>(v));  // xor4 (row_half_mirror)
    v = fmaxf(v, dpp_mov_f<0x140>(v));  // xor8 (row_mirror)
    if constexpr (GB == 6) {
        v = fmaxf(v, __shfl_xor(v, 16));
        v = fmaxf(v, __shfl_xor(v, 32));
    }
    return v;
}

template<int GB>
__device__ __forceinline__ float groupSum(float v) {
    v += dpp_mov_f<0x0B1>(v);
    v += dpp_mov_f<0x04E>(v);
    v += dpp_mov_f<0x141>(v);
    v += dpp_mov_f<0x140>(v);
    if constexpr (GB == 6) {
        v += __shfl_xor(v, 16);
        v += __shfl_xor(v, 32);
    }
    return v;
}

__device__ __forceinline__ void loadW(const float* __restrict__ W, int col,
                                      f32x4* wv) {
#pragma unroll
    for (int i = 0; i < 16; ++i) {
        wv[i].x = W[(size_t)(4 * i + 0) * TT + col];
        wv[i].y = W[(size_t)(4 * i + 1) * TT + col];
        wv[i].z = W[(size_t)(4 * i + 2) * TT + col];
        wv[i].w = W[(size_t)(4 * i + 3) * TT + col];
    }
}

__device__ __forceinline__ float hsum(f32x4 s) {
    return (s.x + s.y) + (s.z + s.w);
}

// 4 independent dots vs the same W column (plain loop, compiler-scheduled;
// R9 lesson: manual pipelining of this regresses 2.2x).
__device__ __forceinline__ void dot4(const float* __restrict__ x0p,
                                     const f32x4* wv, float* xw) {
    const f32x4* xr0 = (const f32x4*)(x0p);
    const f32x4* xr1 = (const f32x4*)(x0p + DD);
    const f32x4* xr2 = (const f32x4*)(x0p + 2 * DD);
    const f32x4* xr3 = (const f32x4*)(x0p + 3 * DD);
    f32x4 s0 = {0.f, 0.f, 0.f, 0.f};
    f32x4 s1 = {0.f, 0.f, 0.f, 0.f};
    f32x4 s2 = {0.f, 0.f, 0.f, 0.f};
    f32x4 s3 = {0.f, 0.f, 0.f, 0.f};
#pragma unroll
    for (int i = 0; i < 16; ++i) {
        const f32x4 w = wv[i];
        s0 += xr0[i] * w;
        s1 += xr1[i] * w;
        s2 += xr2[i] * w;
        s3 += xr3[i] * w;
    }
    xw[0] = hsum(s0); xw[1] = hsum(s1); xw[2] = hsum(s2); xw[3] = hsum(s3);
}

// Pass A: per-(b, t, segment) sum of log-probs (log2 units). At its issue
// floor (~65 us, R5) — unchanged.
template<int SEG>
__global__ __launch_bounds__(256, 4)
void segsum_kernel(const float* __restrict__ data,
                   const float* __restrict__ targets,
                   const float* __restrict__ W,
                   float* __restrict__ segsum)
{
    constexpr int NSEG = NN / SEG;
    const int blk   = blockIdx.x;
    const int s     = blk % SEG;
    const int rem   = blk / SEG;
    const int chunk = rem % CHUNKS;
    const int b     = rem / CHUNKS;
    const int tid   = threadIdx.x;
    const int col   = chunk * 256 + tid;

    f32x4 wv[16];
    loadW(W, col, wv);

    const float* xb = data + (size_t)b * NN * DD;
    const float* tb = targets + (size_t)b * NN;

    const int n0 = s * NSEG;
    float acc = 0.0f;
    for (int n = n0; n < n0 + NSEG; n += 4) {
        float xw[4];
        dot4(xb + (size_t)n * DD, wv, xw);
#pragma unroll
        for (int j = 0; j < 4; ++j) {
            const float d = tb[n + j] - xw[j];
            acc = fmaf(d * d, NLOG2E_HALF, acc);
        }
    }
    segsum[((size_t)b * SEG + s) * TT + col] = acc;
}

// Pass B: dual-stream scan, DE-LOCKSTEPPED: 128-thread blocks, each of the
// 2 waves owns a DIFFERENT segment-pair over the same 64 columns. Waves on
// a SIMD follow independent n-streams, so per-quad scalar-load misses
// stagger instead of hitting all co-resident waves simultaneously.
// Per-wave instruction stream identical to R12 -> bitwise-equal partials.
template<int SEG, int GB>
__global__ __launch_bounds__(128)
void scan2_kernel(const float* __restrict__ data,
                  const float* __restrict__ targets,
                  const float* __restrict__ W,
                  const float* __restrict__ segsum,
                  float* __restrict__ mP,
                  float* __restrict__ sP,
                  float* __restrict__ pP)
{
    constexpr int NSEG = NN / SEG;
    constexpr int HALF = SEG / 2;             // 8 segment-pairs
    constexpr int SPB  = 4;                   // segment-pairs per block (2 waves x ... )
    constexpr int PPN  = TT >> GB;            // partials per (b,n)
    const int blk   = blockIdx.x;
    const int sp2   = blk % SPB;              // which pair-of-pairs
    const int rem   = blk / SPB;
    const int cg    = rem % (TT / 64);        // 64-column group
    const int b     = rem / (TT / 64);
    const int tid   = threadIdx.x;
    const int wave  = tid >> 6;               // 0 or 1
    const int lane  = tid & 63;
    const int col   = cg * 64 + lane;

    const int sA = sp2 * 2 + wave;            // [0,8): this wave's segment
    const int sB = sA + HALF;

    f32x4 wv[16];
    loadW(W, col, wv);

    const float* xb = data + (size_t)b * NN * DD;
    const float* tb = targets + (size_t)b * NN;

    const int  k      = (col & ~((1 << GB) - 1)) >> GB;
    const bool writer = (lane & ((1 << GB) - 1)) == 0;
    const size_t base0 = (size_t)b * NN * PPN + k;

    // exclusive segment prefixes for both streams (log2 units)
    float alphaA = 0.0f, alphaB = 0.0f;
    for (int s2 = 0; s2 < sB; ++s2) {
        const float v = segsum[((size_t)b * SEG + s2) * TT + col];
        alphaB += v;
        if (s2 < sA) alphaA += v;
    }

    // full softmax+emit for one quad of one stream; updates that alpha.
    auto quad = [&](float& alpha, int n) {
        float xw[4];
        dot4(xb + (size_t)n * DD, wv, xw);
        float a[4];
        float al = alpha;
#pragma unroll
        for (int j = 0; j < 4; ++j) {
            a[j] = al;
            const float d = tb[n + j] - xw[j];
            al = fmaf(d * d, NLOG2E_HALF, al);
        }
        alpha = al;
        float m[4], e[4], qv[4], sv[4], pv[4];
#pragma unroll
        for (int j = 0; j < 4; ++j) m[j] = groupMax<GB>(a[j]);
#pragma unroll
        for (int j = 0; j < 4; ++j) {
            e[j]  = exp2_fast(a[j] - m[j]);
            qv[j] = e[j] * xw[j];
        }
#pragma unroll
        for (int j = 0; j < 4; ++j) sv[j] = groupSum<GB>(e[j]);
#pragma unroll
        for (int j = 0; j < 4; ++j) pv[j] = groupSum<GB>(qv[j]);
        if (writer) {
            const size_t i0 = base0 + (size_t)n * PPN;
#pragma unroll
            for (int j = 0; j < 4; ++j) {
                mP[i0 + (size_t)j * PPN] = m[j];
                sP[i0 + (size_t)j * PPN] = sv[j];
                pP[i0 + (size_t)j * PPN] = pv[j];
            }
        }
    };

    const int nA0 = sA * NSEG;
    const int nB0 = sB * NSEG;
#pragma unroll 1
    for (int i = 0; i < NSEG; i += 4) {
        quad(alphaA, nA0 + i);   // two independent streams interleave to
        quad(alphaB, nB0 + i);   // fill dependency stalls
    }
}

// Single-stream scan (fallback path only).
template<int SEG, int GB>
__global__ __launch_bounds__(256, 4)
void scan_kernel(const float* __restrict__ data,
                 const float* __restrict__ targets,
                 const float* __restrict__ W,
                 const float* __restrict__ segsum,
                 float* __restrict__ mP,
                 float* __restrict__ sP,
                 float* __restrict__ pP)
{
    constexpr int NSEG = NN / SEG;
    constexpr int PPN  = TT >> GB;
    const int blk   = blockIdx.x;
    const int s     = blk % SEG;
    const int rem   = blk / SEG;
    const int chunk = rem % CHUNKS;
    const int b     = rem / CHUNKS;
    const int tid   = threadIdx.x;
    const int lane  = tid & 63;
    const int col   = chunk * 256 + tid;

    f32x4 wv[16];
    loadW(W, col, wv);

    const float* xb = data + (size_t)b * NN * DD;
    const float* tb = targets + (size_t)b * NN;

    const int  k      = (chunk * 256 + (tid & ~((1 << GB) - 1))) >> GB;
    const bool writer = (lane & ((1 << GB) - 1)) == 0;
    const size_t base0 = (size_t)b * NN * PPN + k;

    float alpha = 0.0f;
    if constexpr (SEG > 1) {
        for (int s2 = 0; s2 < s; ++s2)
            alpha += segsum[((size_t)b * SEG + s2) * TT + col];
    }

    const int n0 = s * NSEG;
    for (int n = n0; n < n0 + NSEG; n += 4) {
        float xw[4];
        dot4(xb + (size_t)n * DD, wv, xw);
        float a[4];
        float al = alpha;
#pragma unroll
        for (int j = 0; j < 4; ++j) {
            a[j] = al;
            const float d = tb[n + j] - xw[j];
            al = fmaf(d * d, NLOG2E_HALF, al);
        }
        alpha = al;
        float m[4], e[4], qv[4], sv[4], pv[4];
#pragma unroll
        for (int j = 0; j < 4; ++j) m[j] = groupMax<GB>(a[j]);
#pragma unroll
        for (int j = 0; j < 4; ++j) {
            e[j]  = exp2_fast(a[j] - m[j]);
            qv[j] = e[j] * xw[j];
        }
#pragma unroll
        for (int j = 0; j < 4; ++j) sv[j] = groupSum<GB>(e[j]);
#pragma unroll
        for (int j = 0; j < 4; ++j) pv[j] = groupSum<GB>(qv[j]);
        if (writer) {
            const size_t i0 = base0 + (size_t)n * PPN;
#pragma unroll
            for (int j = 0; j < 4; ++j) {
                mP[i0 + (size_t)j * PPN] = m[j];
                sP[i0 + (size_t)j * PPN] = sv[j];
                pP[i0 + (size_t)j * PPN] = pv[j];
            }
        }
    }
}

// Pass C: one wave per (b,n): merge PPN partials (log2 units).
template<int PPN>
__global__ __launch_bounds__(256)
void combine_kernel(const float* __restrict__ mP,
                    const float* __restrict__ sP,
                    const float* __restrict__ pP,
                    float* __restrict__ out)
{
    const int wgid = blockIdx.x * 4 + (threadIdx.x >> 6);   // = b*NN + n
    const int lane = threadIdx.x & 63;
    const size_t base = (size_t)wgid * PPN;

    float m = -INFINITY, s = 0.0f, p = 0.0f;
    if constexpr (PPN >= 64) {
#pragma unroll
        for (int j = 0; j < PPN / 64; ++j) {
            const size_t idx = base + lane + j * 64;
            const float mk = mP[idx], sk = sP[idx], pk = pP[idx];
            const float M  = fmaxf(m, mk);
            const float e1 = exp2_fast(m - M), e2 = exp2_fast(mk - M);
            s = s * e1 + sk * e2;
            p = p * e1 + pk * e2;
            m = M;
        }
    } else {
        if (lane < PPN) {
            m = mP[base + lane]; s = sP[base + lane]; p = pP[base + lane];
        }
    }

#pragma unroll
    for (int off = 1; off < 64; off <<= 1) {
        const float mo = __shfl_xor(m, off);
        const float so = __shfl_xor(s, off);
        const float po = __shfl_xor(p, off);
        const float M  = fmaxf(m, mo);
        const float e1 = exp2_fast(m - M), e2 = exp2_fast(mo - M);
        s = s * e1 + so * e2;
        p = p * e1 + po * e2;
        m = M;
    }

    if (lane == 0) out[wgid] = p / s;
}

extern "C" void kernel_launch(void* const* d_in, const int* in_sizes, int n_in,
                              void* d_out, int out_size, void* d_ws, size_t ws_size,
                              hipStream_t stream)
{
    (void)in_sizes; (void)n_in; (void)out_size;
    const float* data    = (const float*)d_in[0];
    const float* targets = (const float*)d_in[1];
    const float* W       = (const float*)d_in[2];
    float* out = (float*)d_out;

    const size_t plane4 = (size_t)BB * NN * (TT >> 4);   // GB=4: 128 partials/(b,n)
    const size_t plane6 = (size_t)BB * NN * (TT >> 6);   // GB=6: 32 partials/(b,n)
    const size_t seg16  = (size_t)BB * SEGS * TT;

    const int scan2_grid = BB * (TT / 64) * 4;           // 4096 blocks of 128

    if (ws_size >= (3 * plane4 + seg16) * sizeof(float)) {
        // ~54 MB path: SEG=16, GB=4, de-lockstepped dual-stream scan
        float* mP = (float*)d_ws;
        float* sP = mP + plane4;
        float* pP = sP + plane4;
        float* sg = pP + plane4;
        segsum_kernel<SEGS><<<BB * CHUNKS * SEGS, 256, 0, stream>>>(data, targets, W, sg);
        scan2_kernel<SEGS, 4><<<scan2_grid, 128, 0, stream>>>(data, targets, W, sg, mP, sP, pP);
        combine_kernel<128><<<(BB * NN) / 4, 256, 0, stream>>>(mP, sP, pP, out);
    } else if (ws_size >= (3 * plane6 + seg16) * sizeof(float)) {
        // ~17 MB path: SEG=16, GB=6
        float* mP = (float*)d_ws;
        float* sP = mP + plane6;
        float* pP = sP + plane6;
        float* sg = pP + plane6;
        segsum_kernel<SEGS><<<BB * CHUNKS * SEGS, 256, 0, stream>>>(data, targets, W, sg);
        scan2_kernel<SEGS, 6><<<scan2_grid, 128, 0, stream>>>(data, targets, W, sg, mP, sP, pP);
        combine_kernel<32><<<(BB * NN) / 4, 256, 0, stream>>>(mP, sP, pP, out);
    } else {
        // 12 MB fallback: no segmentation (slow but correct)
        float* mP = (float*)d_ws;
        float* sP = mP + plane6;
        float* pP = sP + plane6;
        scan_kernel<1, 6><<<BB * CHUNKS, 256, 0, stream>>>(data, targets, W, nullptr, mP, sP, pP);
        combine_kernel<32><<<(BB * NN) / 4, 256, 0, stream>>>(mP, sP, pP, out);
    }
}

// Round 14
// 302.374 us; speedup vs baseline: 2.2693x; 2.2693x over previous
//
#include <hip/hip_runtime.h>
#include <hip/hip_bf16.h>
#include <math.h>

// Problem constants (from reference setup_inputs)
#define BB 32
#define NN 1024
#define DD 64
#define TT 2048
#define CHUNKS (TT / 256)   // 8 column-chunks of 256
#define SEGS 16             // n-segments (decoupled scan)

typedef float f32x4 __attribute__((ext_vector_type(4)));

// alpha in LOG2 units: exp() becomes bare v_exp_f32. Validated R9/R10/R12.
#define NLOG2E_HALF (-0.72134752044448169f)   // -0.5 * log2(e)

__device__ __forceinline__ float exp2_fast(float x) {
    return __builtin_amdgcn_exp2f(x);
}

// DPP move WITHOUT tied-old operand -> fuses into the consumer op.
template<int CTRL>
__device__ __forceinline__ float dpp_mov_f(float v) {
    return __int_as_float(
        __builtin_amdgcn_mov_dpp(__float_as_int(v), CTRL, 0xF, 0xF, true));
}

// All-lanes butterfly reduce over groups of 2^GB lanes.
template<int GB>
__device__ __forceinline__ float groupMax(float v) {
    v = fmaxf(v, dpp_mov_f<0x0B1>(v));  // xor1
    v = fmaxf(v, dpp_mov_f<0x04E>(v));  // xor2
    v = fmaxf(v, dpp_mov_f<0x141>(v));  // xor4 (row_half_mirror)
    v = fmaxf(v, dpp_mov_f<0x140>(v));  // xor8 (row_mirror)
    if constexpr (GB == 6) {
        v = fmaxf(v, __shfl_xor(v, 16));
        v = fmaxf(v, __shfl_xor(v, 32));
    }
    return v;
}

template<int GB>
__device__ __forceinline__ float groupSum(float v) {
    v += dpp_mov_f<0x0B1>(v);
    v += dpp_mov_f<0x04E>(v);
    v += dpp_mov_f<0x141>(v);
    v += dpp_mov_f<0x140>(v);
    if constexpr (GB == 6) {
        v += __shfl_xor(v, 16);
        v += __shfl_xor(v, 32);
    }
    return v;
}

__device__ __forceinline__ void loadW(const float* __restrict__ W, int col,
                                      f32x4* wv) {
#pragma unroll
    for (int i = 0; i < 16; ++i) {
        wv[i].x = W[(size_t)(4 * i + 0) * TT + col];
        wv[i].y = W[(size_t)(4 * i + 1) * TT + col];
        wv[i].z = W[(size_t)(4 * i + 2) * TT + col];
        wv[i].w = W[(size_t)(4 * i + 3) * TT + col];
    }
}

__device__ __forceinline__ float hsum(f32x4 s) {
    return (s.x + s.y) + (s.z + s.w);
}

// 4 independent dots vs the same W column (plain loop, compiler-scheduled;
// R9 lesson: manual pipelining regresses 2.2x). Address math from a
// blockIdx-derived n keeps x loads SCALAR (R13 lesson: a tid-derived n
// kills s_load scalarization, 3x regression).
__device__ __forceinline__ void dot4(const float* __restrict__ x0p,
                                     const f32x4* wv, float* xw) {
    const f32x4* xr0 = (const f32x4*)(x0p);
    const f32x4* xr1 = (const f32x4*)(x0p + DD);
    const f32x4* xr2 = (const f32x4*)(x0p + 2 * DD);
    const f32x4* xr3 = (const f32x4*)(x0p + 3 * DD);
    f32x4 s0 = {0.f, 0.f, 0.f, 0.f};
    f32x4 s1 = {0.f, 0.f, 0.f, 0.f};
    f32x4 s2 = {0.f, 0.f, 0.f, 0.f};
    f32x4 s3 = {0.f, 0.f, 0.f, 0.f};
#pragma unroll
    for (int i = 0; i < 16; ++i) {
        const f32x4 w = wv[i];
        s0 += xr0[i] * w;
        s1 += xr1[i] * w;
        s2 += xr2[i] * w;
        s3 += xr3[i] * w;
    }
    xw[0] = hsum(s0); xw[1] = hsum(s1); xw[2] = hsum(s2); xw[3] = hsum(s3);
}

// Pass A: per-(b, t, segment) sum of log-probs (log2 units). At its issue
// floor (~65 us, R5) — unchanged.
template<int SEG>
__global__ __launch_bounds__(256, 4)
void segsum_kernel(const float* __restrict__ data,
                   const float* __restrict__ targets,
                   const float* __restrict__ W,
                   float* __restrict__ segsum)
{
    constexpr int NSEG = NN / SEG;
    const int blk   = blockIdx.x;
    const int s     = blk % SEG;
    const int rem   = blk / SEG;
    const int chunk = rem % CHUNKS;
    const int b     = rem / CHUNKS;
    const int tid   = threadIdx.x;
    const int col   = chunk * 256 + tid;

    f32x4 wv[16];
    loadW(W, col, wv);

    const float* xb = data + (size_t)b * NN * DD;
    const float* tb = targets + (size_t)b * NN;

    const int n0 = s * NSEG;
    float acc = 0.0f;
    for (int n = n0; n < n0 + NSEG; n += 4) {
        float xw[4];
        dot4(xb + (size_t)n * DD, wv, xw);
#pragma unroll
        for (int j = 0; j < 4; ++j) {
            const float d = tb[n + j] - xw[j];
            acc = fmaf(d * d, NLOG2E_HALF, acc);
        }
    }
    segsum[((size_t)b * SEG + s) * TT + col] = acc;
}

// Pass B: QUAD-stream scan. R12 geometry (256-thread block; all 4 waves
// share the same segment set and 256 columns -> scalar x loads + full-line
// partial writes), but each wave runs FOUR independent segment streams
// (s, s+4, s+8, s+12). Independent alpha chains give the compiler 4x the
// ILP material to fill DPP/exp dependency stalls. Per-stream FP order
// identical to R12 -> bitwise-equal partials.
template<int SEG, int GB>
__global__ __launch_bounds__(256)
void scan4_kernel(const float* __restrict__ data,
                  const float* __restrict__ targets,
                  const float* __restrict__ W,
                  const float* __restrict__ segsum,
                  float* __restrict__ mP,
                  float* __restrict__ sP,
                  float* __restrict__ pP)
{
    constexpr int NSEG = NN / SEG;
    constexpr int QTR  = SEG / 4;             // 4 stream-base slots
    constexpr int PPN  = TT >> GB;            // partials per (b,n)
    const int blk   = blockIdx.x;
    const int sA    = blk % QTR;              // base segment (0..3)
    const int rem   = blk / QTR;
    const int chunk = rem % CHUNKS;
    const int b     = rem / CHUNKS;
    const int tid   = threadIdx.x;
    const int lane  = tid & 63;
    const int col   = chunk * 256 + tid;

    const int s0 = sA, s1 = sA + QTR, s2 = sA + 2 * QTR, s3 = sA + 3 * QTR;

    f32x4 wv[16];
    loadW(W, col, wv);

    const float* xb = data + (size_t)b * NN * DD;
    const float* tb = targets + (size_t)b * NN;

    const int  k      = (chunk * 256 + (tid & ~((1 << GB) - 1))) >> GB;
    const bool writer = (lane & ((1 << GB) - 1)) == 0;
    const size_t base0 = (size_t)b * NN * PPN + k;

    // exclusive segment prefixes for the 4 streams (log2 units)
    float alpha0 = 0.0f, alpha1 = 0.0f, alpha2 = 0.0f, alpha3 = 0.0f;
    for (int s2i = 0; s2i < SEG - 1; ++s2i) {
        const float v = segsum[((size_t)b * SEG + s2i) * TT + col];
        if (s2i < s0) alpha0 += v;
        if (s2i < s1) alpha1 += v;
        if (s2i < s2) alpha2 += v;
        if (s2i < s3) alpha3 += v;
    }

    // full softmax+emit for one quad of one stream; updates that alpha.
    auto quad = [&](float& alpha, int n) {
        float xw[4];
        dot4(xb + (size_t)n * DD, wv, xw);
        float a[4];
        float al = alpha;
#pragma unroll
        for (int j = 0; j < 4; ++j) {
            a[j] = al;
            const float d = tb[n + j] - xw[j];
            al = fmaf(d * d, NLOG2E_HALF, al);
        }
        alpha = al;
        float m[4], e[4], qv[4], sv[4], pv[4];
#pragma unroll
        for (int j = 0; j < 4; ++j) m[j] = groupMax<GB>(a[j]);
#pragma unroll
        for (int j = 0; j < 4; ++j) {
            e[j]  = exp2_fast(a[j] - m[j]);
            qv[j] = e[j] * xw[j];
        }
#pragma unroll
        for (int j = 0; j < 4; ++j) sv[j] = groupSum<GB>(e[j]);
#pragma unroll
        for (int j = 0; j < 4; ++j) pv[j] = groupSum<GB>(qv[j]);
        if (writer) {
            const size_t i0 = base0 + (size_t)n * PPN;
#pragma unroll
            for (int j = 0; j < 4; ++j) {
                mP[i0 + (size_t)j * PPN] = m[j];
                sP[i0 + (size_t)j * PPN] = sv[j];
                pP[i0 + (size_t)j * PPN] = pv[j];
            }
        }
    };

    const int n00 = s0 * NSEG;
    const int n01 = s1 * NSEG;
    const int n02 = s2 * NSEG;
    const int n03 = s3 * NSEG;
#pragma unroll 1
    for (int i = 0; i < NSEG; i += 4) {
        quad(alpha0, n00 + i);   // four independent streams: the compiler
        quad(alpha1, n01 + i);   // interleaves them to fill dep stalls
        quad(alpha2, n02 + i);
        quad(alpha3, n03 + i);
    }
}

// Single-stream scan (fallback path only).
template<int SEG, int GB>
__global__ __launch_bounds__(256, 4)
void scan_kernel(const float* __restrict__ data,
                 const float* __restrict__ targets,
                 const float* __restrict__ W,
                 const float* __restrict__ segsum,
                 float* __restrict__ mP,
                 float* __restrict__ sP,
                 float* __restrict__ pP)
{
    constexpr int NSEG = NN / SEG;
    constexpr int PPN  = TT >> GB;
    const int blk   = blockIdx.x;
    const int s     = blk % SEG;
    const int rem   = blk / SEG;
    const int chunk = rem % CHUNKS;
    const int b     = rem / CHUNKS;
    const int tid   = threadIdx.x;
    const int lane  = tid & 63;
    const int col   = chunk * 256 + tid;

    f32x4 wv[16];
    loadW(W, col, wv);

    const float* xb = data + (size_t)b * NN * DD;
    const float* tb = targets + (size_t)b * NN;

    const int  k      = (chunk * 256 + (tid & ~((1 << GB) - 1))) >> GB;
    const bool writer = (lane & ((1 << GB) - 1)) == 0;
    const size_t base0 = (size_t)b * NN * PPN + k;

    float alpha = 0.0f;
    if constexpr (SEG > 1) {
        for (int s2 = 0; s2 < s; ++s2)
            alpha += segsum[((size_t)b * SEG + s2) * TT + col];
    }

    const int n0 = s * NSEG;
    for (int n = n0; n < n0 + NSEG; n += 4) {
        float xw[4];
        dot4(xb + (size_t)n * DD, wv, xw);
        float a[4];
        float al = alpha;
#pragma unroll
        for (int j = 0; j < 4; ++j) {
            a[j] = al;
            const float d = tb[n + j] - xw[j];
            al = fmaf(d * d, NLOG2E_HALF, al);
        }
        alpha = al;
        float m[4], e[4], qv[4], sv[4], pv[4];
#pragma unroll
        for (int j = 0; j < 4; ++j) m[j] = groupMax<GB>(a[j]);
#pragma unroll
        for (int j = 0; j < 4; ++j) {
            e[j]  = exp2_fast(a[j] - m[j]);
            qv[j] = e[j] * xw[j];
        }
#pragma unroll
        for (int j = 0; j < 4; ++j) sv[j] = groupSum<GB>(e[j]);
#pragma unroll
        for (int j = 0; j < 4; ++j) pv[j] = groupSum<GB>(qv[j]);
        if (writer) {
            const size_t i0 = base0 + (size_t)n * PPN;
#pragma unroll
            for (int j = 0; j < 4; ++j) {
                mP[i0 + (size_t)j * PPN] = m[j];
                sP[i0 + (size_t)j * PPN] = sv[j];
                pP[i0 + (size_t)j * PPN] = pv[j];
            }
        }
    }
}

// Pass C: one wave per (b,n): merge PPN partials (log2 units).
template<int PPN>
__global__ __launch_bounds__(256)
void combine_kernel(const float* __restrict__ mP,
                    const float* __restrict__ sP,
                    const float* __restrict__ pP,
                    float* __restrict__ out)
{
    const int wgid = blockIdx.x * 4 + (threadIdx.x >> 6);   // = b*NN + n
    const int lane = threadIdx.x & 63;
    const size_t base = (size_t)wgid * PPN;

    float m = -INFINITY, s = 0.0f, p = 0.0f;
    if constexpr (PPN >= 64) {
#pragma unroll
        for (int j = 0; j < PPN / 64; ++j) {
            const size_t idx = base + lane + j * 64;
            const float mk = mP[idx], sk = sP[idx], pk = pP[idx];
            const float M  = fmaxf(m, mk);
            const float e1 = exp2_fast(m - M), e2 = exp2_fast(mk - M);
            s = s * e1 + sk * e2;
            p = p * e1 + pk * e2;
            m = M;
        }
    } else {
        if (lane < PPN) {
            m = mP[base + lane]; s = sP[base + lane]; p = pP[base + lane];
        }
    }

#pragma unroll
    for (int off = 1; off < 64; off <<= 1) {
        const float mo = __shfl_xor(m, off);
        const float so = __shfl_xor(s, off);
        const float po = __shfl_xor(p, off);
        const float M  = fmaxf(m, mo);
        const float e1 = exp2_fast(m - M), e2 = exp2_fast(mo - M);
        s = s * e1 + so * e2;
        p = p * e1 + po * e2;
        m = M;
    }

    if (lane == 0) out[wgid] = p / s;
}

extern "C" void kernel_launch(void* const* d_in, const int* in_sizes, int n_in,
                              void* d_out, int out_size, void* d_ws, size_t ws_size,
                              hipStream_t stream)
{
    (void)in_sizes; (void)n_in; (void)out_size;
    const float* data    = (const float*)d_in[0];
    const float* targets = (const float*)d_in[1];
    const float* W       = (const float*)d_in[2];
    float* out = (float*)d_out;

    const size_t plane4 = (size_t)BB * NN * (TT >> 4);   // GB=4: 128 partials/(b,n)
    const size_t plane6 = (size_t)BB * NN * (TT >> 6);   // GB=6: 32 partials/(b,n)
    const size_t seg16  = (size_t)BB * SEGS * TT;

    const int scan4_grid = BB * CHUNKS * (SEGS / 4);     // 1024 blocks of 256

    if (ws_size >= (3 * plane4 + seg16) * sizeof(float)) {
        // ~54 MB path: SEG=16, GB=4, quad-stream scan
        float* mP = (float*)d_ws;
        float* sP = mP + plane4;
        float* pP = sP + plane4;
        float* sg = pP + plane4;
        segsum_kernel<SEGS><<<BB * CHUNKS * SEGS, 256, 0, stream>>>(data, targets, W, sg);
        scan4_kernel<SEGS, 4><<<scan4_grid, 256, 0, stream>>>(data, targets, W, sg, mP, sP, pP);
        combine_kernel<128><<<(BB * NN) / 4, 256, 0, stream>>>(mP, sP, pP, out);
    } else if (ws_size >= (3 * plane6 + seg16) * sizeof(float)) {
        // ~17 MB path: SEG=16, GB=6, quad-stream scan
        float* mP = (float*)d_ws;
        float* sP = mP + plane6;
        float* pP = sP + plane6;
        float* sg = pP + plane6;
        segsum_kernel<SEGS><<<BB * CHUNKS * SEGS, 256, 0, stream>>>(data, targets, W, sg);
        scan4_kernel<SEGS, 6><<<scan4_grid, 256, 0, stream>>>(data, targets, W, sg, mP, sP, pP);
        combine_kernel<32><<<(BB * NN) / 4, 256, 0, stream>>>(mP, sP, pP, out);
    } else {
        // 12 MB fallback: no segmentation (slow but correct)
        float* mP = (float*)d_ws;
        float* sP = mP + plane6;
        float* pP = sP + plane6;
        scan_kernel<1, 6><<<BB * CHUNKS, 256, 0, stream>>>(data, targets, W, nullptr, mP, sP, pP);
        combine_kernel<32><<<(BB * NN) / 4, 256, 0, stream>>>(mP, sP, pP, out);
    }
}